// Round 1
// baseline (1745.975 us; speedup 1.0000x reference)
//
#include <hip/hip_runtime.h>
#include <hip/hip_bf16.h>

// ---- problem constants ----
#define B_      64
#define HW_     56        // H == W == 56
#define C_      192
#define HEADS_  6
#define HD_     32
#define WS_     7
#define TOK_    49
#define NW_     64        // windows per image (8x8)
#define NWIN_   4096      // B_*NW_
#define M_      200704    // NWIN_*TOK_
#define C3_     576
#define HID_    768
#define SHIFT_  3

typedef unsigned short ushort_t;
typedef __bf16 bf16v8 __attribute__((ext_vector_type(8)));
typedef float  f32x4  __attribute__((ext_vector_type(4)));

__device__ inline float bf2f(ushort_t u) {
  union { unsigned int i; float f; } c; c.i = ((unsigned int)u) << 16; return c.f;
}
__device__ inline ushort_t f2bf(float f) {
  union { float f; unsigned int u; } c; c.f = f;
  unsigned int u = c.u;
  return (ushort_t)((u + 0x7fffu + ((u >> 16) & 1u)) >> 16);  // RNE
}
__device__ inline bf16v8 ld8(const ushort_t* p) { return *(const bf16v8*)p; }

// ---- fp32 -> bf16 weight convert ----
__global__ __launch_bounds__(256) void k_f2b(const float* __restrict__ s,
                                             ushort_t* __restrict__ d, int n) {
  int i = blockIdx.x * 256 + threadIdx.x;
  if (i < n) d[i] = f2bf(s[i]);
}

// ---- LN1 + roll(-3,-3) + window partition gather: x (B,H,W,C) -> xw bf16 (M,192) ----
__global__ __launch_bounds__(256) void k_ln1(const float* __restrict__ x,
                                             const float* __restrict__ g,
                                             const float* __restrict__ b,
                                             ushort_t* __restrict__ xw) {
  int wave = threadIdx.x >> 6, lane = threadIdx.x & 63;
  int gtok = blockIdx.x * 4 + wave;           // window-order token index
  int win = gtok / 49, tok = gtok - win * 49;
  int bb = win >> 6, nw = win & 63;
  int wr = nw >> 3, wc = nw & 7;
  int ii = tok / 7, jj = tok - ii * 7;
  int hh = wr * 7 + ii + SHIFT_; if (hh >= HW_) hh -= HW_;
  int ww = wc * 7 + jj + SHIFT_; if (ww >= HW_) ww -= HW_;
  const float* row = x + ((size_t)bb * 3136 + hh * 56 + ww) * C_;
  float vals[3]; float s = 0.f, s2 = 0.f;
  #pragma unroll
  for (int r = 0; r < 3; ++r) { float t = row[lane + 64 * r]; vals[r] = t; s += t; s2 += t * t; }
  #pragma unroll
  for (int o = 32; o; o >>= 1) { s += __shfl_xor(s, o); s2 += __shfl_xor(s2, o); }
  float mean = s * (1.f / 192.f);
  float var  = s2 * (1.f / 192.f) - mean * mean;
  float rstd = rsqrtf(var + 1e-5f);
  ushort_t* orow = xw + (size_t)gtok * C_;
  #pragma unroll
  for (int r = 0; r < 3; ++r) {
    int c = lane + 64 * r;
    orow[c] = f2bf((vals[r] - mean) * rstd * g[c] + b[c]);
  }
}

// ---- QKV GEMM: xw (M,192) @ wq^T (576,192) + bias -> q,k,v (nwin,heads,tok,hd) bf16 ----
__global__ __launch_bounds__(256) void k_qkv(const ushort_t* __restrict__ xw,
                                             const ushort_t* __restrict__ wq,
                                             const float* __restrict__ qkvb,
                                             ushort_t* __restrict__ q,
                                             ushort_t* __restrict__ k,
                                             ushort_t* __restrict__ v) {
  int wave = threadIdx.x >> 6, lane = threadIdx.x & 63;
  int lr = lane & 15, lk = (lane >> 4) * 8;
  int mbase = blockIdx.x * 128 + wave * 32;
  int nbase = blockIdx.y * 64;
  bf16v8 a[2][6];
  #pragma unroll
  for (int rt = 0; rt < 2; ++rt)
    #pragma unroll
    for (int kk = 0; kk < 6; ++kk)
      a[rt][kk] = ld8(xw + (size_t)(mbase + rt * 16 + lr) * C_ + kk * 32 + lk);
  for (int nt = 0; nt < 4; ++nt) {
    int ncol = nbase + nt * 16 + lr;          // D col = lane&15
    f32x4 acc0 = {0.f, 0.f, 0.f, 0.f}, acc1 = {0.f, 0.f, 0.f, 0.f};
    #pragma unroll
    for (int kk = 0; kk < 6; ++kk) {
      bf16v8 bb = ld8(wq + (size_t)ncol * C_ + kk * 32 + lk);
      acc0 = __builtin_amdgcn_mfma_f32_16x16x32_bf16(a[0][kk], bb, acc0, 0, 0, 0);
      acc1 = __builtin_amdgcn_mfma_f32_16x16x32_bf16(a[1][kk], bb, acc1, 0, 0, 0);
    }
    float bias = qkvb[ncol];
    int sec = ncol / 192, cm = ncol - sec * 192;
    int head = cm >> 5, dd = cm & 31;
    ushort_t* dst = sec == 0 ? q : (sec == 1 ? k : v);
    #pragma unroll
    for (int rt = 0; rt < 2; ++rt) {
      f32x4 acc = rt ? acc1 : acc0;
      #pragma unroll
      for (int i = 0; i < 4; ++i) {
        int gg = mbase + rt * 16 + (lane >> 4) * 4 + i;   // D row
        int win = gg / 49, tok = gg - win * 49;
        dst[((size_t)(win * 6 + head) * 49 + tok) * 32 + dd] = f2bf(acc[i] + bias);
      }
    }
  }
}

// ---- attention per (window, head) ----
__global__ __launch_bounds__(256) void k_attn(const ushort_t* __restrict__ q,
                                              const ushort_t* __restrict__ k,
                                              const ushort_t* __restrict__ v,
                                              const float* __restrict__ rpb,
                                              const int* __restrict__ relidx,
                                              const float* __restrict__ amask,
                                              ushort_t* __restrict__ aout) {
  __shared__ ushort_t qs[49 * 32];
  __shared__ ushort_t kst[32 * 52];   // transposed [d][kc], padded
  __shared__ ushort_t vs[49 * 32];
  __shared__ float S[49][52];
  int wh = blockIdx.x;
  int win = wh / 6, head = wh - win * 6;
  int nw = win & 63;
  const size_t base = (size_t)wh * (49 * 32);
  for (int idx = threadIdx.x; idx < 49 * 32; idx += 256) {
    int kc = idx >> 5, d = idx & 31;
    qs[idx] = q[base + idx];
    kst[d * 52 + kc] = k[base + idx];
    vs[idx] = v[base + idx];
  }
  __syncthreads();
  const float scale = 0.17677669529663687f;  // 1/sqrt(32)
  for (int p = threadIdx.x; p < 49 * 49; p += 256) {
    int qr = p / 49, kc = p - qr * 49;
    float acc = 0.f;
    #pragma unroll
    for (int d = 0; d < 32; ++d)
      acc += bf2f(qs[qr * 32 + d]) * bf2f(kst[d * 52 + kc]);
    float bias = rpb[relidx[p] * 6 + head];
    float mval = amask[(size_t)nw * (49 * 49) + p];
    S[qr][kc] = acc * scale + bias + mval;
  }
  __syncthreads();
  int wave = threadIdx.x >> 6, lane = threadIdx.x & 63;
  for (int r = wave; r < 49; r += 4) {
    float val = lane < 49 ? S[r][lane] : -1e30f;
    float mx = val;
    #pragma unroll
    for (int o = 32; o; o >>= 1) mx = fmaxf(mx, __shfl_xor(mx, o));
    float e = lane < 49 ? __expf(val - mx) : 0.f;
    float sm = e;
    #pragma unroll
    for (int o = 32; o; o >>= 1) sm += __shfl_xor(sm, o);
    if (lane < 49) S[r][lane] = e / sm;
  }
  __syncthreads();
  for (int idx = threadIdx.x; idx < 49 * 32; idx += 256) {
    int qr = idx >> 5, d = idx & 31;
    float acc = 0.f;
    #pragma unroll
    for (int kc = 0; kc < 49; ++kc)
      acc += S[qr][kc] * bf2f(vs[kc * 32 + d]);
    aout[(size_t)(win * 49 + qr) * C_ + head * 32 + d] = f2bf(acc);
  }
}

// ---- proj GEMM + reverse window/roll scatter + residual: writes x2 into d_out ----
__global__ __launch_bounds__(256) void k_proj(const ushort_t* __restrict__ ain,
                                              const ushort_t* __restrict__ wp,
                                              const float* __restrict__ pb,
                                              const float* __restrict__ x0,
                                              float* __restrict__ x2) {
  int wave = threadIdx.x >> 6, lane = threadIdx.x & 63;
  int lr = lane & 15, lk = (lane >> 4) * 8;
  int mbase = blockIdx.x * 128 + wave * 32;
  int nbase = blockIdx.y * 64;
  bf16v8 a[2][6];
  #pragma unroll
  for (int rt = 0; rt < 2; ++rt)
    #pragma unroll
    for (int kk = 0; kk < 6; ++kk)
      a[rt][kk] = ld8(ain + (size_t)(mbase + rt * 16 + lr) * C_ + kk * 32 + lk);
  for (int nt = 0; nt < 4; ++nt) {
    int ncol = nbase + nt * 16 + lr;
    f32x4 acc0 = {0.f, 0.f, 0.f, 0.f}, acc1 = {0.f, 0.f, 0.f, 0.f};
    #pragma unroll
    for (int kk = 0; kk < 6; ++kk) {
      bf16v8 bb = ld8(wp + (size_t)ncol * C_ + kk * 32 + lk);
      acc0 = __builtin_amdgcn_mfma_f32_16x16x32_bf16(a[0][kk], bb, acc0, 0, 0, 0);
      acc1 = __builtin_amdgcn_mfma_f32_16x16x32_bf16(a[1][kk], bb, acc1, 0, 0, 0);
    }
    float bias = pb[ncol];
    #pragma unroll
    for (int rt = 0; rt < 2; ++rt) {
      f32x4 acc = rt ? acc1 : acc0;
      #pragma unroll
      for (int i = 0; i < 4; ++i) {
        int gg = mbase + rt * 16 + (lane >> 4) * 4 + i;
        int win = gg / 49, tok = gg - win * 49;
        int bb2 = win >> 6, nw = win & 63;
        int wr = nw >> 3, wc = nw & 7;
        int ii = tok / 7, jj = tok - ii * 7;
        int hh = wr * 7 + ii + SHIFT_; if (hh >= HW_) hh -= HW_;
        int ww = wc * 7 + jj + SHIFT_; if (ww >= HW_) ww -= HW_;
        size_t dst = ((size_t)bb2 * 3136 + hh * 56 + ww) * C_ + ncol;
        x2[dst] = x0[dst] + acc[i] + bias;
      }
    }
  }
}

// ---- LN2: x2 (d_out) -> y2 bf16 ----
__global__ __launch_bounds__(256) void k_ln2(const float* __restrict__ x2,
                                             const float* __restrict__ g,
                                             const float* __restrict__ b,
                                             ushort_t* __restrict__ y2) {
  int wave = threadIdx.x >> 6, lane = threadIdx.x & 63;
  int gtok = blockIdx.x * 4 + wave;
  const float* row = x2 + (size_t)gtok * C_;
  float vals[3]; float s = 0.f, s2 = 0.f;
  #pragma unroll
  for (int r = 0; r < 3; ++r) { float t = row[lane + 64 * r]; vals[r] = t; s += t; s2 += t * t; }
  #pragma unroll
  for (int o = 32; o; o >>= 1) { s += __shfl_xor(s, o); s2 += __shfl_xor(s2, o); }
  float mean = s * (1.f / 192.f);
  float var  = s2 * (1.f / 192.f) - mean * mean;
  float rstd = rsqrtf(var + 1e-5f);
  ushort_t* orow = y2 + (size_t)gtok * C_;
  #pragma unroll
  for (int r = 0; r < 3; ++r) {
    int c = lane + 64 * r;
    orow[c] = f2bf((vals[r] - mean) * rstd * g[c] + b[c]);
  }
}

// ---- fused MLP: fc1 + exact GELU (LDS) + fc2 + bias + residual RMW on d_out ----
__global__ __launch_bounds__(256) void k_mlp(const ushort_t* __restrict__ y2,
                                             const ushort_t* __restrict__ w1,
                                             const float* __restrict__ b1,
                                             const ushort_t* __restrict__ w2,
                                             const float* __restrict__ b2,
                                             float* __restrict__ out) {
  __shared__ ushort_t hid[32][HID_ + 8];
  int wave = threadIdx.x >> 6, lane = threadIdx.x & 63;
  int lr = lane & 15, lk = (lane >> 4) * 8;
  int mbase = blockIdx.x * 32;
  // fc1: 32 rows x 768 cols; wave covers cols [wave*192, wave*192+192)
  bf16v8 a[2][6];
  #pragma unroll
  for (int rt = 0; rt < 2; ++rt)
    #pragma unroll
    for (int kk = 0; kk < 6; ++kk)
      a[rt][kk] = ld8(y2 + (size_t)(mbase + rt * 16 + lr) * C_ + kk * 32 + lk);
  for (int nt = 0; nt < 12; ++nt) {
    int ncol = wave * 192 + nt * 16 + lr;
    f32x4 acc0 = {0.f, 0.f, 0.f, 0.f}, acc1 = {0.f, 0.f, 0.f, 0.f};
    #pragma unroll
    for (int kk = 0; kk < 6; ++kk) {
      bf16v8 bb = ld8(w1 + (size_t)ncol * C_ + kk * 32 + lk);
      acc0 = __builtin_amdgcn_mfma_f32_16x16x32_bf16(a[0][kk], bb, acc0, 0, 0, 0);
      acc1 = __builtin_amdgcn_mfma_f32_16x16x32_bf16(a[1][kk], bb, acc1, 0, 0, 0);
    }
    float bias = b1[ncol];
    #pragma unroll
    for (int rt = 0; rt < 2; ++rt) {
      f32x4 acc = rt ? acc1 : acc0;
      #pragma unroll
      for (int i = 0; i < 4; ++i) {
        int rl = rt * 16 + (lane >> 4) * 4 + i;
        float xv = acc[i] + bias;
        float gl = 0.5f * xv * (1.f + erff(xv * 0.70710678118654752f));
        hid[rl][ncol] = f2bf(gl);
      }
    }
  }
  __syncthreads();
  // fc2: 32 rows x 192 cols; wave covers cols [wave*48, wave*48+48), K=768
  for (int ct = 0; ct < 3; ++ct) {
    int ncol = wave * 48 + ct * 16 + lr;
    f32x4 acc0 = {0.f, 0.f, 0.f, 0.f}, acc1 = {0.f, 0.f, 0.f, 0.f};
    for (int kk = 0; kk < 24; ++kk) {
      bf16v8 a0 = ld8(&hid[lr][kk * 32 + lk]);
      bf16v8 a1 = ld8(&hid[16 + lr][kk * 32 + lk]);
      bf16v8 bb = ld8(w2 + (size_t)ncol * HID_ + kk * 32 + lk);
      acc0 = __builtin_amdgcn_mfma_f32_16x16x32_bf16(a0, bb, acc0, 0, 0, 0);
      acc1 = __builtin_amdgcn_mfma_f32_16x16x32_bf16(a1, bb, acc1, 0, 0, 0);
    }
    float bias = b2[ncol];
    #pragma unroll
    for (int rt = 0; rt < 2; ++rt) {
      f32x4 acc = rt ? acc1 : acc0;
      #pragma unroll
      for (int i = 0; i < 4; ++i) {
        int gg = mbase + rt * 16 + (lane >> 4) * 4 + i;
        size_t o = (size_t)gg * C_ + ncol;
        out[o] = out[o] + acc[i] + bias;   // out currently holds x2
      }
    }
  }
}

extern "C" void kernel_launch(void* const* d_in, const int* in_sizes, int n_in,
                              void* d_out, int out_size, void* d_ws, size_t ws_size,
                              hipStream_t stream) {
  const float* x     = (const float*)d_in[0];
  const float* n1g   = (const float*)d_in[1];
  const float* n1b   = (const float*)d_in[2];
  const float* qkvw  = (const float*)d_in[3];
  const float* qkvb  = (const float*)d_in[4];
  const float* rpb   = (const float*)d_in[5];
  const float* projw = (const float*)d_in[6];
  const float* projb = (const float*)d_in[7];
  const float* n2g   = (const float*)d_in[8];
  const float* n2b   = (const float*)d_in[9];
  const float* fc1w  = (const float*)d_in[10];
  const float* fc1b  = (const float*)d_in[11];
  const float* fc2w  = (const float*)d_in[12];
  const float* fc2b  = (const float*)d_in[13];
  const int*   relidx= (const int*)d_in[14];
  const float* amask = (const float*)d_in[15];
  float* out = (float*)d_out;

  const size_t MC = (size_t)M_ * C_;
  ushort_t* ws = (ushort_t*)d_ws;
  ushort_t* xw = ws;                 // (M,192) bf16; later reused as attn_out
  ushort_t* q  = ws + MC;            // (nwin,heads,tok,hd); later reused as y2
  ushort_t* k  = ws + 2 * MC;
  ushort_t* v  = ws + 3 * MC;
  ushort_t* wq = ws + 4 * MC;
  ushort_t* wp = wq + (size_t)C3_ * C_;
  ushort_t* w1 = wp + (size_t)C_ * C_;
  ushort_t* w2 = w1 + (size_t)HID_ * C_;

  k_f2b<<<(C3_ * C_ + 255) / 256, 256, 0, stream>>>(qkvw, wq, C3_ * C_);
  k_f2b<<<(C_ * C_ + 255) / 256, 256, 0, stream>>>(projw, wp, C_ * C_);
  k_f2b<<<(HID_ * C_ + 255) / 256, 256, 0, stream>>>(fc1w, w1, HID_ * C_);
  k_f2b<<<(C_ * HID_ + 255) / 256, 256, 0, stream>>>(fc2w, w2, C_ * HID_);

  k_ln1<<<M_ / 4, 256, 0, stream>>>(x, n1g, n1b, xw);
  k_qkv<<<dim3(M_ / 128, C3_ / 64), 256, 0, stream>>>(xw, wq, qkvb, q, k, v);
  k_attn<<<NWIN_ * HEADS_, 256, 0, stream>>>(q, k, v, rpb, relidx, amask, xw);
  k_proj<<<dim3(M_ / 128, C_ / 64), 256, 0, stream>>>(xw, wp, projb, x, out);
  k_ln2<<<M_ / 4, 256, 0, stream>>>(out, n2g, n2b, q);
  k_mlp<<<M_ / 32, 256, 0, stream>>>(q, w1, fc1b, w2, fc2b, out);
}